// Round 5
// baseline (1147.925 us; speedup 1.0000x reference)
//
#include <hip/hip_runtime.h>

// Problem constants
constexpr int NB = 8;    // batch
constexpr int NC = 32;   // channels
constexpr int NV = 512;  // vertices
constexpr int NL = 256;  // features
constexpr float F_ALPHA = 0.05f;
constexpr float F_BETA  = 0.95f;   // == 1 - F_ALPHA (used for both roles)

typedef __bf16 bf16x8 __attribute__((ext_vector_type(8)));
typedef float  f32x4  __attribute__((ext_vector_type(4)));

// async global->LDS, 16B per lane; LDS dest = wave-uniform base + lane*16
__device__ __forceinline__ void async_ld16(const void* g, void* l) {
  __builtin_amdgcn_global_load_lds(
      (const __attribute__((address_space(1))) void*)g,
      (__attribute__((address_space(3))) void*)l, 16, 0, 0);
}

// ---------------- prep kernels ----------------

// partial column sums of adj: partial[n, chunk, w] = sum_{v in chunk*64..+64} adj[n,v,w]
__global__ void k_colsum_part(const float* __restrict__ adj, float* __restrict__ partial) {
  int idx = blockIdx.x * 256 + threadIdx.x;       // NB*8*NV = 32768
  int w = idx & 511;
  int chunk = (idx >> 9) & 7;
  int n = idx >> 12;
  const float* p = adj + n * (NV * NV) + chunk * 64 * NV + w;
  float s = 0.f;
#pragma unroll
  for (int v = 0; v < 64; ++v) s += p[v * NV];
  partial[idx] = s;
}

__global__ void k_dinv(const float* __restrict__ partial, float* __restrict__ dinv) {
  int idx = blockIdx.x * 256 + threadIdx.x;       // NB*NV = 4096
  int w = idx & 511;
  int n = idx >> 9;
  float s = 1.f;                                   // +1 from the identity on the diagonal
#pragma unroll
  for (int j = 0; j < 8; ++j) s += partial[n * 4096 + j * 512 + w];
  dinv[idx] = 1.f / s;
}

// a_bf16[n,v,w] = (adj[n,v,w] + (v==w)) * dinv[n,w]
__global__ void k_prep_a(const float* __restrict__ adj, const float* __restrict__ dinv,
                         __bf16* __restrict__ a) {
  int idx = blockIdx.x * 256 + threadIdx.x;       // NB*NV*NV
  int w = idx & 511;
  int v = (idx >> 9) & 511;
  int n = idx >> 18;
  float val = adj[idx] + (v == w ? 1.0f : 0.0f);
  a[idx] = (__bf16)(val * dinv[(n << 9) | w]);
}

// Wt[l,k] = W[k,l] in bf16
__global__ void k_prep_wt(const float* __restrict__ W, __bf16* __restrict__ Wt) {
  int idx = blockIdx.x * 256 + threadIdx.x;       // 65536
  int l = idx >> 8, k = idx & 255;
  Wt[idx] = (__bf16)W[(k << 8) | l];
}

// Folded conv weights, k-major: cwT[k][o], 96 x 32 fp32 (12 KiB).
//   k <  32 (x group):  Wx[o,k] + alpha*(W1[o,k] + W2[o,k])   [since h_g = alpha*x + beta*D_g]
//   32<=k<64 (D1 group): beta*W1[o,k-32]
//   64<=k<96 (D2 group): beta*W2[o,k-64]
__global__ void k_prep_cwt(const float* __restrict__ cw, float* __restrict__ cwT) {
  int idx = blockIdx.x * 256 + threadIdx.x;       // 3072
  if (idx < 3072) {
    int k = idx >> 5, o = idx & 31;
    float v;
    if (k < 32)      v = cw[o * 96 + k] + F_ALPHA * (cw[o * 96 + 32 + k] + cw[o * 96 + 64 + k]);
    else             v = F_BETA * cw[o * 96 + k];
    cwT[idx] = v;
  }
}

// ---------------- GEMM 1: hw^T = Wt @ B^T (+ epilogue) ----------------
// Per pair p=(n,c): acc[l][w] = sum_k Wt[l][k] * B[w][k], stored at hw[n,c,l,w].
// BF32: B-source is fp32 (x, layout [n,c,v,l]); else bf16 (D1, layout [n,v,c,l]).
// EPI 0: hw = acc + b[l]                       (first propagation: hw1 = xW + b)
// EPI 1: hw = alpha*hwprev + beta*(acc + b[l]) (second: hw2 = alpha*hw1 + beta*(D1*W + b),
//                                              exact since h1 = alpha*x + beta*D1, xW = hw1 - b)
template <bool BF32, int EPI>
__global__ __launch_bounds__(256, 2)
void k_gemm_wt(const __bf16* __restrict__ Wt, const void* __restrict__ Bsrc,
               const float* __restrict__ bias, __bf16* __restrict__ hw,
               const __bf16* __restrict__ hwprev) {
  __shared__ __align__(16) char lds[32768];
  char* ldsA = lds;
  char* ldsB = lds + 16384;

  const int tid = threadIdx.x;
  const int bid = blockIdx.x;
  const int p = bid >> 3;            // pair index n*NC+c
  const int mtile = (bid >> 2) & 1;  // M=256 -> 2 tiles of 128
  const int ntile = bid & 3;         // N=512 -> 4 tiles of 128
  const int n = p >> 5, c = p & 31;

  int Bbase, Bstride;
  if (BF32) { Bbase = p * (NV * NL); Bstride = NL; }               // x[n,c,w,k]
  else      { Bbase = n * (NV * NC * NL) + c * NL; Bstride = NC * NL; } // D1[n,w,c,k]

  const int wave = tid >> 6, lane = tid & 63;
  const int quad = lane >> 4, l16 = lane & 15;
  const int wm = wave >> 1, wn = wave & 1;
  const int wbase = (tid & ~63) * 16;

  f32x4 acc[4][4];
#pragma unroll
  for (int i = 0; i < 4; ++i)
#pragma unroll
    for (int j = 0; j < 4; ++j) acc[i][j] = (f32x4){0.f, 0.f, 0.f, 0.f};

  for (int kt = 0; kt < 256 / 64; ++kt) {
    __syncthreads();
    // stage A = Wt tile [128 x 64], swizzled
#pragma unroll
    for (int j = 0; j < 4; ++j) {
      int pos = j * 4096 + tid * 16;
      int row = pos >> 7;
      int kb = (pos & 127) ^ ((row & 7) * 16);
      const __bf16* g = Wt + (mtile * 128 + row) * 256 + kt * 64 + (kb >> 1);
      async_ld16(g, ldsA + j * 4096 + wbase);
    }
    // stage B tile [128 x 64]
    if (BF32) {
      const float* Bf = (const float*)Bsrc;
#pragma unroll
      for (int j = 0; j < 4; ++j) {
        int pos = j * 4096 + tid * 16;
        int row = pos >> 7;
        int kb = (pos & 127) ^ ((row & 7) * 16);
        const float* g = Bf + Bbase + (ntile * 128 + row) * Bstride + kt * 64 + (kb >> 1);
        float4 f0 = *(const float4*)g;
        float4 f1 = *(const float4*)(g + 4);
        bf16x8 vv;
        vv[0] = (__bf16)f0.x; vv[1] = (__bf16)f0.y; vv[2] = (__bf16)f0.z; vv[3] = (__bf16)f0.w;
        vv[4] = (__bf16)f1.x; vv[5] = (__bf16)f1.y; vv[6] = (__bf16)f1.z; vv[7] = (__bf16)f1.w;
        *(bf16x8*)(ldsB + pos) = vv;
      }
    } else {
      const __bf16* Bf = (const __bf16*)Bsrc;
#pragma unroll
      for (int j = 0; j < 4; ++j) {
        int pos = j * 4096 + tid * 16;
        int row = pos >> 7;
        int kb = (pos & 127) ^ ((row & 7) * 16);
        const __bf16* g = Bf + Bbase + (ntile * 128 + row) * Bstride + kt * 64 + (kb >> 1);
        async_ld16(g, ldsB + j * 4096 + wbase);
      }
    }
    __syncthreads();
#pragma unroll
    for (int ks = 0; ks < 2; ++ks) {
      bf16x8 af[4], bfr[4];
#pragma unroll
      for (int mb = 0; mb < 4; ++mb) {
        int m = wm * 64 + mb * 16 + l16;
        int kb = (ks * 64 + quad * 16) ^ ((m & 7) * 16);
        af[mb] = *(const bf16x8*)(ldsA + m * 128 + kb);
      }
#pragma unroll
      for (int nb = 0; nb < 4; ++nb) {
        int nn = wn * 64 + nb * 16 + l16;
        int kb = (ks * 64 + quad * 16) ^ ((nn & 7) * 16);
        bfr[nb] = *(const bf16x8*)(ldsB + nn * 128 + kb);
      }
#pragma unroll
      for (int mb = 0; mb < 4; ++mb)
#pragma unroll
        for (int nb = 0; nb < 4; ++nb)
          acc[mb][nb] = __builtin_amdgcn_mfma_f32_16x16x32_bf16(af[mb], bfr[nb], acc[mb][nb], 0, 0, 0);
    }
  }
  // epilogue: hw[n,c, l, w]
  const size_t obase = (size_t)p * (NL * NV) + mtile * 128 * NV + ntile * 128;
  __bf16* outp = hw + obase;
  const __bf16* prevp = (EPI == 1) ? hwprev + obase : nullptr;
#pragma unroll
  for (int mb = 0; mb < 4; ++mb) {
#pragma unroll
    for (int r = 0; r < 4; ++r) {
      int ml = wm * 64 + mb * 16 + quad * 4 + r;
      float bv = bias[mtile * 128 + ml];
#pragma unroll
      for (int nb = 0; nb < 4; ++nb) {
        int nl = wn * 64 + nb * 16 + l16;
        if (EPI == 0) {
          outp[ml * NV + nl] = (__bf16)(acc[mb][nb][r] + bv);
        } else {
          float pv = (float)prevp[ml * NV + nl];
          outp[ml * NV + nl] = (__bf16)(F_ALPHA * pv + F_BETA * (acc[mb][nb][r] + bv));
        }
      }
    }
  }
}

// ---------------- GEMM 2: D = a @ hw (raw diffusion term, no x epilogue) ----------------
// Per batch n: D[v, col=(c,l)] = sum_w a[n,v,w] * hw[n,c,l,w]; D[n,v,c,l] out (bf16).
__global__ __launch_bounds__(256, 2)
void k_gemm_a(const __bf16* __restrict__ abuf, const __bf16* __restrict__ hw,
              __bf16* __restrict__ dout) {
  __shared__ __align__(16) char lds[32768];
  char* ldsA = lds;
  char* ldsB = lds + 16384;

  const int tid = threadIdx.x;
  const int bid = blockIdx.x;
  const int n = bid >> 8;
  const int mtile = (bid >> 6) & 3;  // M=512 -> 4
  const int ntile = bid & 63;        // N=8192 -> 64

  const __bf16* Ab = abuf + n * (NV * NV) + mtile * 128 * NV;        // rows v, stride 512
  const __bf16* Bb = hw + n * (NC * NL * NV) + ntile * 128 * NV;     // rows col, stride 512

  const int wave = tid >> 6, lane = tid & 63;
  const int quad = lane >> 4, l16 = lane & 15;
  const int wm = wave >> 1, wn = wave & 1;
  const int wbase = (tid & ~63) * 16;

  f32x4 acc[4][4];
#pragma unroll
  for (int i = 0; i < 4; ++i)
#pragma unroll
    for (int j = 0; j < 4; ++j) acc[i][j] = (f32x4){0.f, 0.f, 0.f, 0.f};

  for (int kt = 0; kt < 512 / 64; ++kt) {
    __syncthreads();
#pragma unroll
    for (int j = 0; j < 4; ++j) {
      int pos = j * 4096 + tid * 16;
      int row = pos >> 7;
      int kb = (pos & 127) ^ ((row & 7) * 16);
      async_ld16(Ab + row * NV + kt * 64 + (kb >> 1), ldsA + j * 4096 + wbase);
    }
#pragma unroll
    for (int j = 0; j < 4; ++j) {
      int pos = j * 4096 + tid * 16;
      int row = pos >> 7;
      int kb = (pos & 127) ^ ((row & 7) * 16);
      async_ld16(Bb + row * NV + kt * 64 + (kb >> 1), ldsB + j * 4096 + wbase);
    }
    __syncthreads();
#pragma unroll
    for (int ks = 0; ks < 2; ++ks) {
      bf16x8 af[4], bfr[4];
#pragma unroll
      for (int mb = 0; mb < 4; ++mb) {
        int m = wm * 64 + mb * 16 + l16;
        int kb = (ks * 64 + quad * 16) ^ ((m & 7) * 16);
        af[mb] = *(const bf16x8*)(ldsA + m * 128 + kb);
      }
#pragma unroll
      for (int nb = 0; nb < 4; ++nb) {
        int nn = wn * 64 + nb * 16 + l16;
        int kb = (ks * 64 + quad * 16) ^ ((nn & 7) * 16);
        bfr[nb] = *(const bf16x8*)(ldsB + nn * 128 + kb);
      }
#pragma unroll
      for (int mb = 0; mb < 4; ++mb)
#pragma unroll
        for (int nb = 0; nb < 4; ++nb)
          acc[mb][nb] = __builtin_amdgcn_mfma_f32_16x16x32_bf16(af[mb], bfr[nb], acc[mb][nb], 0, 0, 0);
    }
  }
  // epilogue: D[n, v, col] = acc (raw; alpha/beta folded into consumers)
#pragma unroll
  for (int mb = 0; mb < 4; ++mb) {
#pragma unroll
    for (int r = 0; r < 4; ++r) {
      int v = mtile * 128 + wm * 64 + mb * 16 + quad * 4 + r;
#pragma unroll
      for (int nb = 0; nb < 4; ++nb) {
        int col = ntile * 128 + wn * 64 + nb * 16 + l16;
        dout[n * (NV * NC * NL) + v * (NC * NL) + col] = (__bf16)acc[mb][nb][r];
      }
    }
  }
}

// ---------------- conv (VALU, split-c): out[n,o,v,l] = cb[o] + sum folded-weights * {x,D1,D2} ----
// 512 threads/block: half h in {0,1} reduces c in [h*16, h*16+16) for all 32 o's;
// partials exchanged through 32 KB LDS (l-consecutive -> conflict-free); half h
// finalizes and stores o in [h*16, h*16+16). 4 blocks/CU = 32 waves/CU (100% occ);
// per-wave serial FMA chain halves vs the 256-thread version -> 2x latency slack.
__global__ __launch_bounds__(512, 8)
void k_conv_valu(const float* __restrict__ x, const __bf16* __restrict__ d1,
                 const __bf16* __restrict__ d2, const float* __restrict__ cwT,
                 const float* __restrict__ cb, float* __restrict__ out) {
  __shared__ float xch[32][256];   // 32 KiB exchange buffer
  const int bid = blockIdx.x;
  const int n = bid >> 9, v = bid & 511;
  const int tid = threadIdx.x;
  const int half = tid >> 8;       // 0: c = 0..15, 1: c = 16..31
  const int l = tid & 255;
  const int c0 = half << 4;

  const float*  xp = x  + n * (NC * NV * NL) + v * NL + l;    // + c*NV*NL
  const __bf16* p1 = d1 + (n * NV + v) * (NC * NL) + l;       // + c*NL
  const __bf16* p2 = d2 + (n * NV + v) * (NC * NL) + l;

  float acc[32];
#pragma unroll
  for (int o = 0; o < 32; ++o) acc[o] = 0.f;

#pragma unroll 2
  for (int cc = 0; cc < 16; ++cc) {
    const int c = c0 + cc;
    float xv = xp[c * (NV * NL)];
    float v1 = (float)p1[c * NL];
    float v2 = (float)p2[c * NL];
    const float* wx = cwT + c * 32;
    const float* w1 = cwT + (32 + c) * 32;
    const float* w2 = cwT + (64 + c) * 32;
#pragma unroll
    for (int o = 0; o < 32; ++o)
      acc[o] = fmaf(wx[o], xv, fmaf(w1[o], v1, fmaf(w2[o], v2, acc[o])));
  }

  // hand the other half's o-range over LDS (unique writer per (o,l))
  const int oo = (half ^ 1) << 4;
#pragma unroll
  for (int j = 0; j < 16; ++j) xch[oo + j][l] = acc[oo + j];
  __syncthreads();

  const int om = half << 4;
  float* op = out + (n * NC * NV + v) * NL + l;    // out[((n*NC+o)*NV+v)*NL+l]
#pragma unroll
  for (int j = 0; j < 16; ++j) {
    const int o = om + j;
    op[o * (NV * NL)] = acc[o] + xch[o][l] + cb[o];
  }
}

// ---------------- launch ----------------
extern "C" void kernel_launch(void* const* d_in, const int* in_sizes, int n_in,
                              void* d_out, int out_size, void* d_ws, size_t ws_size,
                              hipStream_t stream) {
  const float* x   = (const float*)d_in[0];
  const float* adj = (const float*)d_in[1];
  const float* W   = (const float*)d_in[2];
  const float* b   = (const float*)d_in[3];
  const float* cw  = (const float*)d_in[4];
  const float* cb  = (const float*)d_in[5];
  float* out = (float*)d_out;
  char* ws = (char*)d_ws;

  // workspace layout (196.3 MiB total — byte-identical footprint to the verified round-0/2)
  float*  dinv    = (float*)ws;                               // 16 KiB
  float*  partial = (float*)(ws + 16384);                     // 128 KiB (dead after k_dinv)
  __bf16* Wt      = (__bf16*)(ws + 147456);                   // 128 KiB
  __bf16* abuf    = (__bf16*)(ws + 278528);                   // 4 MiB
  __bf16* slot1   = (__bf16*)(ws + 4472832);                  // 64 MiB: hwA, then D2
  __bf16* slot2   = (__bf16*)(ws + 4472832 + 67108864);       // 64 MiB: D1
  __bf16* slot3   = (__bf16*)(ws + 4472832 + 2 * 67108864);   // 64 MiB: hwB
  // cwT (12 KiB) reuses the partial region after k_dinv has consumed it
  float*  cwT     = partial;

  __bf16* hwA = slot1;
  __bf16* D1  = slot2;
  __bf16* hwB = slot3;
  __bf16* D2  = slot1;   // hwA dead after k_gemm_wt<false,1>

  k_colsum_part<<<128, 256, 0, stream>>>(adj, partial);
  k_dinv<<<16, 256, 0, stream>>>(partial, dinv);
  k_prep_cwt<<<12, 256, 0, stream>>>(cw, cwT);
  k_prep_a<<<8192, 256, 0, stream>>>(adj, dinv, abuf);
  k_prep_wt<<<256, 256, 0, stream>>>(W, Wt);

  // hwA = xW + b
  k_gemm_wt<true, 0><<<2048, 256, 0, stream>>>(Wt, (const void*)x, b, hwA, nullptr);
  // D1 = a @ hwA
  k_gemm_a<<<2048, 256, 0, stream>>>(abuf, hwA, D1);
  // hwB = alpha*hwA + beta*(D1*W + b)   (== h1 @ W + b)
  k_gemm_wt<false, 1><<<2048, 256, 0, stream>>>(Wt, (const void*)D1, b, hwB, hwA);
  // D2 = a @ hwB
  k_gemm_a<<<2048, 256, 0, stream>>>(abuf, hwB, D2);
  // out = cb + (Wx + a(W1+W2))x + bW1*D1 + bW2*D2
  k_conv_valu<<<4096, 512, 0, stream>>>(x, D1, D2, cwT, cb, out);
}

// Round 6
// 507.611 us; speedup vs baseline: 2.2614x; 2.2614x over previous
//
#include <hip/hip_runtime.h>

// Problem constants
constexpr int NB = 8;    // batch
constexpr int NC = 32;   // channels
constexpr int NV = 512;  // vertices
constexpr int NL = 256;  // features
constexpr float F_ALPHA = 0.05f;
constexpr float F_BETA  = 0.95f;   // == 1 - F_ALPHA (used for both roles)

typedef __bf16 bf16x8 __attribute__((ext_vector_type(8)));
typedef float  f32x4  __attribute__((ext_vector_type(4)));

// async global->LDS, 16B per lane; LDS dest = wave-uniform base + lane*16
__device__ __forceinline__ void async_ld16(const void* g, void* l) {
  __builtin_amdgcn_global_load_lds(
      (const __attribute__((address_space(1))) void*)g,
      (__attribute__((address_space(3))) void*)l, 16, 0, 0);
}

// ---------------- prep kernels ----------------

// partial column sums of adj: partial[n, chunk, w] = sum_{v in chunk*64..+64} adj[n,v,w]
__global__ void k_colsum_part(const float* __restrict__ adj, float* __restrict__ partial) {
  int idx = blockIdx.x * 256 + threadIdx.x;       // NB*8*NV = 32768
  int w = idx & 511;
  int chunk = (idx >> 9) & 7;
  int n = idx >> 12;
  const float* p = adj + n * (NV * NV) + chunk * 64 * NV + w;
  float s = 0.f;
#pragma unroll
  for (int v = 0; v < 64; ++v) s += p[v * NV];
  partial[idx] = s;
}

__global__ void k_dinv(const float* __restrict__ partial, float* __restrict__ dinv) {
  int idx = blockIdx.x * 256 + threadIdx.x;       // NB*NV = 4096
  int w = idx & 511;
  int n = idx >> 9;
  float s = 1.f;                                   // +1 from the identity on the diagonal
#pragma unroll
  for (int j = 0; j < 8; ++j) s += partial[n * 4096 + j * 512 + w];
  dinv[idx] = 1.f / s;
}

// a_bf16[n,v,w] = (adj[n,v,w] + (v==w)) * dinv[n,w]
__global__ void k_prep_a(const float* __restrict__ adj, const float* __restrict__ dinv,
                         __bf16* __restrict__ a) {
  int idx = blockIdx.x * 256 + threadIdx.x;       // NB*NV*NV
  int w = idx & 511;
  int v = (idx >> 9) & 511;
  int n = idx >> 18;
  float val = adj[idx] + (v == w ? 1.0f : 0.0f);
  a[idx] = (__bf16)(val * dinv[(n << 9) | w]);
}

// Wt[l,k] = W[k,l] in bf16
__global__ void k_prep_wt(const float* __restrict__ W, __bf16* __restrict__ Wt) {
  int idx = blockIdx.x * 256 + threadIdx.x;       // 65536
  int l = idx >> 8, k = idx & 255;
  Wt[idx] = (__bf16)W[(k << 8) | l];
}

// Folded conv weights, k-major: cwT[k][o], 96 x 32 fp32 (12 KiB).
//   k <  32 (x group):  Wx[o,k] + alpha*(W1[o,k] + W2[o,k])   [since h_g = alpha*x + beta*D_g]
//   32<=k<64 (D1 group): beta*W1[o,k-32]
//   64<=k<96 (D2 group): beta*W2[o,k-64]
__global__ void k_prep_cwt(const float* __restrict__ cw, float* __restrict__ cwT) {
  int idx = blockIdx.x * 256 + threadIdx.x;       // 3072
  if (idx < 3072) {
    int k = idx >> 5, o = idx & 31;
    float v;
    if (k < 32)      v = cw[o * 96 + k] + F_ALPHA * (cw[o * 96 + 32 + k] + cw[o * 96 + 64 + k]);
    else             v = F_BETA * cw[o * 96 + k];
    cwT[idx] = v;
  }
}

// ---------------- GEMM 1: hw^T = Wt @ B^T (+ epilogue) ----------------
// Per pair p=(n,c): acc[l][w] = sum_k Wt[l][k] * B[w][k], stored at hw[n,c,l,w].
// BF32: B-source is fp32 (x, layout [n,c,v,l]); else bf16 (D1, layout [n,v,c,l]).
// EPI 0: hw = acc + b[l]                       (first propagation: hw1 = xW + b)
// EPI 1: hw = alpha*hwprev + beta*(acc + b[l]) (second: hw2 = alpha*hw1 + beta*(D1*W + b),
//                                              exact since h1 = alpha*x + beta*D1, xW = hw1 - b)
template <bool BF32, int EPI>
__global__ __launch_bounds__(256, 2)
void k_gemm_wt(const __bf16* __restrict__ Wt, const void* __restrict__ Bsrc,
               const float* __restrict__ bias, __bf16* __restrict__ hw,
               const __bf16* __restrict__ hwprev) {
  __shared__ __align__(16) char lds[32768];
  char* ldsA = lds;
  char* ldsB = lds + 16384;

  const int tid = threadIdx.x;
  const int bid = blockIdx.x;
  const int p = bid >> 3;            // pair index n*NC+c
  const int mtile = (bid >> 2) & 1;  // M=256 -> 2 tiles of 128
  const int ntile = bid & 3;         // N=512 -> 4 tiles of 128
  const int n = p >> 5, c = p & 31;

  int Bbase, Bstride;
  if (BF32) { Bbase = p * (NV * NL); Bstride = NL; }               // x[n,c,w,k]
  else      { Bbase = n * (NV * NC * NL) + c * NL; Bstride = NC * NL; } // D1[n,w,c,k]

  const int wave = tid >> 6, lane = tid & 63;
  const int quad = lane >> 4, l16 = lane & 15;
  const int wm = wave >> 1, wn = wave & 1;
  const int wbase = (tid & ~63) * 16;

  f32x4 acc[4][4];
#pragma unroll
  for (int i = 0; i < 4; ++i)
#pragma unroll
    for (int j = 0; j < 4; ++j) acc[i][j] = (f32x4){0.f, 0.f, 0.f, 0.f};

  for (int kt = 0; kt < 256 / 64; ++kt) {
    __syncthreads();
    // stage A = Wt tile [128 x 64], swizzled
#pragma unroll
    for (int j = 0; j < 4; ++j) {
      int pos = j * 4096 + tid * 16;
      int row = pos >> 7;
      int kb = (pos & 127) ^ ((row & 7) * 16);
      const __bf16* g = Wt + (mtile * 128 + row) * 256 + kt * 64 + (kb >> 1);
      async_ld16(g, ldsA + j * 4096 + wbase);
    }
    // stage B tile [128 x 64]
    if (BF32) {
      const float* Bf = (const float*)Bsrc;
#pragma unroll
      for (int j = 0; j < 4; ++j) {
        int pos = j * 4096 + tid * 16;
        int row = pos >> 7;
        int kb = (pos & 127) ^ ((row & 7) * 16);
        const float* g = Bf + Bbase + (ntile * 128 + row) * Bstride + kt * 64 + (kb >> 1);
        float4 f0 = *(const float4*)g;
        float4 f1 = *(const float4*)(g + 4);
        bf16x8 vv;
        vv[0] = (__bf16)f0.x; vv[1] = (__bf16)f0.y; vv[2] = (__bf16)f0.z; vv[3] = (__bf16)f0.w;
        vv[4] = (__bf16)f1.x; vv[5] = (__bf16)f1.y; vv[6] = (__bf16)f1.z; vv[7] = (__bf16)f1.w;
        *(bf16x8*)(ldsB + pos) = vv;
      }
    } else {
      const __bf16* Bf = (const __bf16*)Bsrc;
#pragma unroll
      for (int j = 0; j < 4; ++j) {
        int pos = j * 4096 + tid * 16;
        int row = pos >> 7;
        int kb = (pos & 127) ^ ((row & 7) * 16);
        const __bf16* g = Bf + Bbase + (ntile * 128 + row) * Bstride + kt * 64 + (kb >> 1);
        async_ld16(g, ldsB + j * 4096 + wbase);
      }
    }
    __syncthreads();
#pragma unroll
    for (int ks = 0; ks < 2; ++ks) {
      bf16x8 af[4], bfr[4];
#pragma unroll
      for (int mb = 0; mb < 4; ++mb) {
        int m = wm * 64 + mb * 16 + l16;
        int kb = (ks * 64 + quad * 16) ^ ((m & 7) * 16);
        af[mb] = *(const bf16x8*)(ldsA + m * 128 + kb);
      }
#pragma unroll
      for (int nb = 0; nb < 4; ++nb) {
        int nn = wn * 64 + nb * 16 + l16;
        int kb = (ks * 64 + quad * 16) ^ ((nn & 7) * 16);
        bfr[nb] = *(const bf16x8*)(ldsB + nn * 128 + kb);
      }
#pragma unroll
      for (int mb = 0; mb < 4; ++mb)
#pragma unroll
        for (int nb = 0; nb < 4; ++nb)
          acc[mb][nb] = __builtin_amdgcn_mfma_f32_16x16x32_bf16(af[mb], bfr[nb], acc[mb][nb], 0, 0, 0);
    }
  }
  // epilogue: hw[n,c, l, w]
  const size_t obase = (size_t)p * (NL * NV) + mtile * 128 * NV + ntile * 128;
  __bf16* outp = hw + obase;
  const __bf16* prevp = (EPI == 1) ? hwprev + obase : nullptr;
#pragma unroll
  for (int mb = 0; mb < 4; ++mb) {
#pragma unroll
    for (int r = 0; r < 4; ++r) {
      int ml = wm * 64 + mb * 16 + quad * 4 + r;
      float bv = bias[mtile * 128 + ml];
#pragma unroll
      for (int nb = 0; nb < 4; ++nb) {
        int nl = wn * 64 + nb * 16 + l16;
        if (EPI == 0) {
          outp[ml * NV + nl] = (__bf16)(acc[mb][nb][r] + bv);
        } else {
          float pv = (float)prevp[ml * NV + nl];
          outp[ml * NV + nl] = (__bf16)(F_ALPHA * pv + F_BETA * (acc[mb][nb][r] + bv));
        }
      }
    }
  }
}

// ---------------- GEMM 2: D = a @ hw (raw diffusion term, no x epilogue) ----------------
// Per batch n: D[v, col=(c,l)] = sum_w a[n,v,w] * hw[n,c,l,w]; D[n,v,c,l] out (bf16).
__global__ __launch_bounds__(256, 2)
void k_gemm_a(const __bf16* __restrict__ abuf, const __bf16* __restrict__ hw,
              __bf16* __restrict__ dout) {
  __shared__ __align__(16) char lds[32768];
  char* ldsA = lds;
  char* ldsB = lds + 16384;

  const int tid = threadIdx.x;
  const int bid = blockIdx.x;
  const int n = bid >> 8;
  const int mtile = (bid >> 6) & 3;  // M=512 -> 4
  const int ntile = bid & 63;        // N=8192 -> 64

  const __bf16* Ab = abuf + n * (NV * NV) + mtile * 128 * NV;        // rows v, stride 512
  const __bf16* Bb = hw + n * (NC * NL * NV) + ntile * 128 * NV;     // rows col, stride 512

  const int wave = tid >> 6, lane = tid & 63;
  const int quad = lane >> 4, l16 = lane & 15;
  const int wm = wave >> 1, wn = wave & 1;
  const int wbase = (tid & ~63) * 16;

  f32x4 acc[4][4];
#pragma unroll
  for (int i = 0; i < 4; ++i)
#pragma unroll
    for (int j = 0; j < 4; ++j) acc[i][j] = (f32x4){0.f, 0.f, 0.f, 0.f};

  for (int kt = 0; kt < 512 / 64; ++kt) {
    __syncthreads();
#pragma unroll
    for (int j = 0; j < 4; ++j) {
      int pos = j * 4096 + tid * 16;
      int row = pos >> 7;
      int kb = (pos & 127) ^ ((row & 7) * 16);
      async_ld16(Ab + row * NV + kt * 64 + (kb >> 1), ldsA + j * 4096 + wbase);
    }
#pragma unroll
    for (int j = 0; j < 4; ++j) {
      int pos = j * 4096 + tid * 16;
      int row = pos >> 7;
      int kb = (pos & 127) ^ ((row & 7) * 16);
      async_ld16(Bb + row * NV + kt * 64 + (kb >> 1), ldsB + j * 4096 + wbase);
    }
    __syncthreads();
#pragma unroll
    for (int ks = 0; ks < 2; ++ks) {
      bf16x8 af[4], bfr[4];
#pragma unroll
      for (int mb = 0; mb < 4; ++mb) {
        int m = wm * 64 + mb * 16 + l16;
        int kb = (ks * 64 + quad * 16) ^ ((m & 7) * 16);
        af[mb] = *(const bf16x8*)(ldsA + m * 128 + kb);
      }
#pragma unroll
      for (int nb = 0; nb < 4; ++nb) {
        int nn = wn * 64 + nb * 16 + l16;
        int kb = (ks * 64 + quad * 16) ^ ((nn & 7) * 16);
        bfr[nb] = *(const bf16x8*)(ldsB + nn * 128 + kb);
      }
#pragma unroll
      for (int mb = 0; mb < 4; ++mb)
#pragma unroll
        for (int nb = 0; nb < 4; ++nb)
          acc[mb][nb] = __builtin_amdgcn_mfma_f32_16x16x32_bf16(af[mb], bfr[nb], acc[mb][nb], 0, 0, 0);
    }
  }
  // epilogue: D[n, v, col] = acc (raw; alpha/beta folded into consumers)
#pragma unroll
  for (int mb = 0; mb < 4; ++mb) {
#pragma unroll
    for (int r = 0; r < 4; ++r) {
      int v = mtile * 128 + wm * 64 + mb * 16 + quad * 4 + r;
#pragma unroll
      for (int nb = 0; nb < 4; ++nb) {
        int col = ntile * 128 + wn * 64 + nb * 16 + l16;
        dout[n * (NV * NC * NL) + v * (NC * NL) + col] = (__bf16)acc[mb][nb][r];
      }
    }
  }
}

// ---------------- conv (VALU, 2 v's per thread): out[n,o,v,l] = cb[o] + folded-weights . {x,D1,D2} ----
// One thread per (n, v-pair, l) where the pair is (v, v+256). Per c-iteration: 6
// independent coalesced loads + 192 FMAs (weights SGPR-broadcast, shared across both
// v's) -> 2x compute per memory round-trip vs the 1-v version. acc0/acc1 = 64 VGPRs;
// NO __launch_bounds__ cap (round-5 lesson: a 64-VGPR cap spilled acc to scratch,
// 752 MB of HBM scratch traffic, 5.4x slowdown). No LDS.
__global__ void k_conv_valu(const float* __restrict__ x, const __bf16* __restrict__ d1,
                            const __bf16* __restrict__ d2, const float* __restrict__ cwT,
                            const float* __restrict__ cb, float* __restrict__ out) {
  const int bid = blockIdx.x;          // NB * 256 = 2048
  const int n = bid >> 8;
  const int vb = bid & 255;            // handles v = vb and v = vb + 256
  const int l = threadIdx.x;

  const float*  xp0 = x  + n * (NC * NV * NL) + vb * NL + l;   // + c*NV*NL
  const float*  xp1 = xp0 + 256 * NL;
  const __bf16* q10 = d1 + (n * NV + vb) * (NC * NL) + l;      // + c*NL
  const __bf16* q11 = q10 + 256 * (NC * NL);
  const __bf16* q20 = d2 + (n * NV + vb) * (NC * NL) + l;
  const __bf16* q21 = q20 + 256 * (NC * NL);

  float acc0[32], acc1[32];
#pragma unroll
  for (int o = 0; o < 32; ++o) { acc0[o] = 0.f; acc1[o] = 0.f; }

#pragma unroll 2
  for (int c = 0; c < 32; ++c) {
    float xv0 = xp0[c * (NV * NL)];
    float xv1 = xp1[c * (NV * NL)];
    float v10 = (float)q10[c * NL];
    float v11 = (float)q11[c * NL];
    float v20 = (float)q20[c * NL];
    float v21 = (float)q21[c * NL];
    const float* wx = cwT + c * 32;
    const float* w1 = cwT + (32 + c) * 32;
    const float* w2 = cwT + (64 + c) * 32;
#pragma unroll
    for (int o = 0; o < 32; ++o) {
      const float wxo = wx[o], w1o = w1[o], w2o = w2[o];
      acc0[o] = fmaf(wxo, xv0, fmaf(w1o, v10, fmaf(w2o, v20, acc0[o])));
      acc1[o] = fmaf(wxo, xv1, fmaf(w1o, v11, fmaf(w2o, v21, acc1[o])));
    }
  }

  float* op0 = out + (n * NC * NV + vb) * NL + l;   // out[((n*NC+o)*NV+v)*NL+l]
  float* op1 = op0 + 256 * NL;
#pragma unroll
  for (int o = 0; o < 32; ++o) {
    const float bo = cb[o];
    op0[o * (NV * NL)] = acc0[o] + bo;
    op1[o * (NV * NL)] = acc1[o] + bo;
  }
}

// ---------------- launch ----------------
extern "C" void kernel_launch(void* const* d_in, const int* in_sizes, int n_in,
                              void* d_out, int out_size, void* d_ws, size_t ws_size,
                              hipStream_t stream) {
  const float* x   = (const float*)d_in[0];
  const float* adj = (const float*)d_in[1];
  const float* W   = (const float*)d_in[2];
  const float* b   = (const float*)d_in[3];
  const float* cw  = (const float*)d_in[4];
  const float* cb  = (const float*)d_in[5];
  float* out = (float*)d_out;
  char* ws = (char*)d_ws;

  // workspace layout (196.3 MiB total — byte-identical footprint to the verified round-0/2)
  float*  dinv    = (float*)ws;                               // 16 KiB
  float*  partial = (float*)(ws + 16384);                     // 128 KiB (dead after k_dinv)
  __bf16* Wt      = (__bf16*)(ws + 147456);                   // 128 KiB
  __bf16* abuf    = (__bf16*)(ws + 278528);                   // 4 MiB
  __bf16* slot1   = (__bf16*)(ws + 4472832);                  // 64 MiB: hwA, then D2
  __bf16* slot2   = (__bf16*)(ws + 4472832 + 67108864);       // 64 MiB: D1
  __bf16* slot3   = (__bf16*)(ws + 4472832 + 2 * 67108864);   // 64 MiB: hwB
  // cwT (12 KiB) reuses the partial region after k_dinv has consumed it
  float*  cwT     = partial;

  __bf16* hwA = slot1;
  __bf16* D1  = slot2;
  __bf16* hwB = slot3;
  __bf16* D2  = slot1;   // hwA dead after k_gemm_wt<false,1>

  k_colsum_part<<<128, 256, 0, stream>>>(adj, partial);
  k_dinv<<<16, 256, 0, stream>>>(partial, dinv);
  k_prep_cwt<<<12, 256, 0, stream>>>(cw, cwT);
  k_prep_a<<<8192, 256, 0, stream>>>(adj, dinv, abuf);
  k_prep_wt<<<256, 256, 0, stream>>>(W, Wt);

  // hwA = xW + b
  k_gemm_wt<true, 0><<<2048, 256, 0, stream>>>(Wt, (const void*)x, b, hwA, nullptr);
  // D1 = a @ hwA
  k_gemm_a<<<2048, 256, 0, stream>>>(abuf, hwA, D1);
  // hwB = alpha*hwA + beta*(D1*W + b)   (== h1 @ W + b)
  k_gemm_wt<false, 1><<<2048, 256, 0, stream>>>(Wt, (const void*)D1, b, hwB, hwA);
  // D2 = a @ hwB
  k_gemm_a<<<2048, 256, 0, stream>>>(abuf, hwB, D2);
  // out = cb + (Wx + a(W1+W2))x + bW1*D1 + bW2*D2
  k_conv_valu<<<2048, 256, 0, stream>>>(x, D1, D2, cwT, cb, out);
}